// Round 13
// baseline (160.591 us; speedup 1.0000x reference)
//
#include <hip/hip_runtime.h>

#define HH 512
#define WW 512
#define HW (512*512)
#define NB 8
#define ND 16
#define TW 64            // tile width (output)
#define TH 64            // tile height (output)
#define VR 74            // v-sum rows = TH+10
#define PT 90            // LDS pitch (even for float2; 45 pairs, swizzle headroom)

__device__ __forceinline__ int reflect(int v) {
    if (v < 0) v = -v;
    if (v >= HH) v = 2*HH - 2 - v;
    return v;
}

// Pair-granular XOR swizzle: logical pair p of row r lives at word 2*(p ^ (r&3)).
__device__ __forceinline__ float2 ldp(const float* base, int r, int p) {
    return *(const float2*)(base + r*PT + 2*(p ^ (r & 3)));
}
__device__ __forceinline__ void stp(float* base, int r, int p, float2 v) {
    *(float2*)(base + r*PT + 2*(p ^ (r & 3))) = v;
}

// ---------------- Prepass: {mean_I, 1/(var_I+eps)} interleaved float2 ----------------
// (unchanged from R11/R12: 64x32 tiles, vertical-first rings, float2 h-sums)
__global__ __launch_bounds__(256) void img_stats(const float* __restrict__ img,
                                                 float2* __restrict__ miv) {
    const int VRs = 42, PTs = 86, THs = 32, TWs = 64;
    __shared__ __align__(16) float hF[VRs*PTs];
    __shared__ __align__(16) float hP[VRs*PTs];

    int blk  = blockIdx.x;
    int tile = blk & 127;
    int b    = blk >> 7;
    int ty0  = (tile >> 3) * THs;
    int tx0  = (tile & 7)  * TWs;

    const float inv121 = 1.0f/121.0f;
    const float* ib = img + (size_t)b*HW;
    const int t = threadIdx.x;

    if (t < 252) {
        int seg = t / 84, col = t - seg*84;
        int gx = reflect(tx0 - 10 + col);
        const float* icol = ib + gx;
        int vr0 = seg*14;
        float rv[11], rq[11];
        float sv = 0.f, sq = 0.f;
        #pragma unroll
        for (int j = 0; j < 10; ++j) {
            int gy = reflect(ty0 - 10 + vr0 + j);
            float v = icol[gy*WW], q = v*v;
            rv[j] = v; rq[j] = q; sv += v; sq += q;
        }
        #pragma unroll
        for (int k = 0; k < 14; ++k) {
            int vr = vr0 + k;
            int gy = reflect(ty0 + vr);
            float v = icol[gy*WW], q = v*v;
            sv += v; sq += q;
            hF[vr*PTs + col] = sv;
            hP[vr*PTs + col] = sq;
            sv -= rv[k%11]; sq -= rq[k%11];
            rv[(k+10)%11] = v; rq[(k+10)%11] = q;
        }
    }
    __syncthreads();

    if (t < 168) {
        int arr = t & 1;
        int j2  = t >> 1;
        int seg = (j2 >= 42) ? 1 : 0;
        int vr  = j2 - seg*42;
        int xb = seg ? 38 : 0;
        int nout = seg ? 18 : 19;
        float* rA = (arr ? hP : hF) + vr*PTs;
        float2 ring[5];
        float T = 0.f;
        #pragma unroll
        for (int j = 0; j < 5; ++j) {
            float2 v = *(float2*)(rA + xb + 2*j);
            ring[j] = v; T += v.x + v.y;
        }
        #pragma unroll
        for (int k2 = 0; k2 < 19; ++k2) {
            if (k2 < nout) {
                int hc = xb + 2*k2;
                float2 p = *(float2*)(rA + hc + 10);
                float2 q = ring[k2 % 5];
                float O0 = T + p.x;
                float O1 = O0 + p.y - q.x;
                T = O1 - q.y;
                ring[k2 % 5] = p;
                float2 o; o.x = O0*inv121; o.y = O1*inv121;
                *(float2*)(rA + hc + 10*seg) = o;
            }
        }
    }
    __syncthreads();

    float2* mb = miv + (size_t)b*HW;
    for (int i = t; i < THs*TWs; i += 256) {
        int y = i >> 6, x = i & 63;
        int vr = y + 5, hc = x + 5;
        int slot = hc + ((hc >= 38) ? 10 : 0);
        float mI  = hF[vr*PTs + slot];
        float mII = hP[vr*PTs + slot];
        float var = mII - mI*mI;
        float2 o; o.x = mI; o.y = 1.0f / (var + 1e-8f);
        mb[(ty0 + y)*WW + tx0 + x] = o;
    }
}

// ---------------- Main fused kernel: one (b,d) channel, one 64x64 tile, 512 thr --------
// Vertical-first. Phase A scalar; phases B..D2 float2, all via pair-XOR swizzle.
// LDS: hF/hP [74][90] = 53.3 KB -> 3 blocks/CU x 8 waves = 24 waves/CU.
// Logical pair maps (pairs = 2 floats):
//   col-slots after B : sp(c2) = c2 + 5*(c2>=19)   (c2 in 0..36)
//   row-slots after C : prow(y) = y + 10*(y>=32)   (y in 0..63)
//   col map after D   : wp(c2) = c2 + 10*(c2>=16)  (c2 in 0..31)
// Physical = logical-pair ^ (row & 3)  (bijective per row; same-row phases inherit
// all disjointness proofs; C's cross-row writes hit disjoint row ranges).
__global__ __launch_bounds__(512) void guided_main(const float* __restrict__ feat,
                                                   const float* __restrict__ img,
                                                   const float2* __restrict__ miv,
                                                   float* __restrict__ out) {
    __shared__ __align__(16) float hF[VR*PT];
    __shared__ __align__(16) float hP[VR*PT];

    int blk  = blockIdx.x;
    int tile = blk & 63;         // 8 col-tiles x 8 row-tiles
    int bd   = blk >> 6;
    int b    = bd >> 4;
    int ty0  = (tile >> 3) * TH;
    int tx0  = (tile & 7)  * TW;

    const float inv121 = 1.0f/121.0f;
    const float* fb   = feat + (size_t)bd*HW;
    const float* ib   = img  + (size_t)b*HW;
    const float2* mivb = miv + (size_t)b*HW;
    const int t = threadIdx.x;

    // ---- Phase A: vertical raw 11-sums of feat & img*feat (scalar, coalesced) ----
    // 84 cols x 6 row-segs (13 outputs each, guard vr<74) = 504 threads.
    if (t < 504) {
        int seg = t / 84, col = t - seg*84;
        int gx = reflect(tx0 - 10 + col);
        const float* fcol = fb + gx;
        const float* icol = ib + gx;
        int vr0 = seg*13;
        float rf[11], rp[11];
        float sf = 0.f, sp = 0.f;
        #pragma unroll
        for (int j = 0; j < 10; ++j) {
            int gy = reflect(ty0 - 10 + vr0 + j);
            float f = fcol[gy*WW], im = icol[gy*WW];
            float p = f*im;
            rf[j] = f; rp[j] = p; sf += f; sp += p;
        }
        #pragma unroll
        for (int k = 0; k < 13; ++k) {
            int vr = vr0 + k;
            if (vr < VR) {
                int gy = reflect(ty0 + vr);     // = ty0-10 + (vr+10)
                float f = fcol[gy*WW], im = icol[gy*WW];
                float p = f*im;
                sf += f; sp += p;
                int pp = 2*((col >> 1) ^ (vr & 3)) + (col & 1);   // swizzled scalar slot
                hF[vr*PT + pp] = sf;
                hP[vr*PT + pp] = sp;
                sf -= rf[k%11]; sp -= rp[k%11];
                rf[(k+10)%11] = f; rp[(k+10)%11] = p;
            }
        }
    }
    __syncthreads();

    // ---- Phase B: horizontal 11-sums -> mp/cip (x inv121) in place at col-slots ----
    // 74 rows x 2 segs x 2 arrays = 296 threads; waves single-array (arr = t>=148).
    // seg0: reads pairs 0..23, writes 0..18. seg1: reads 19..41, writes 24..41
    // (same row -> same XOR shift -> logical disjointness == physical).
    if (t < 296) {
        int arr = (t >= 148) ? 1 : 0;
        int j   = t - arr*148;
        int seg = (j >= 74) ? 1 : 0;
        int vr  = j - seg*74;
        int xp  = seg ? 19 : 0;              // base pair
        int nout = seg ? 18 : 19;
        float* A = arr ? hP : hF;
        float2 ring[5];
        float T = 0.f;
        #pragma unroll
        for (int j2 = 0; j2 < 5; ++j2) {
            float2 v = ldp(A, vr, xp + j2);
            ring[j2] = v; T += v.x + v.y;
        }
        #pragma unroll
        for (int k2 = 0; k2 < 19; ++k2) {
            if (k2 < nout) {
                float2 p = ldp(A, vr, xp + k2 + 5);
                float2 q = ring[k2 % 5];
                float O0 = T + p.x;
                float O1 = O0 + p.y - q.x;
                T = O1 - q.y;
                ring[k2 % 5] = p;
                float2 o; o.x = O0*inv121; o.y = O1*inv121;
                stp(A, vr, xp + k2 + 5*seg, o);
            }
        }
    }
    __syncthreads();

    // ---- Phase B2: a,b elementwise on pairs; float2 miv loads; in place ----
    for (int i = t; i < VR*37; i += 512) {
        int y = i / 37, c2 = i - y*37;
        int sp = c2 + ((c2 >= 19) ? 5 : 0);
        float2 mp2  = ldp(hF, y, sp);
        float2 cip2 = ldp(hP, y, sp);
        int gy = reflect(ty0 - 5 + y);
        const float2* mrow = mivb + gy*WW;
        int gx0 = tx0 - 5 + 2*c2;
        float2 g0 = mrow[reflect(gx0)];
        float2 g1 = mrow[reflect(gx0+1)];
        float a0 = (cip2.x - g0.x*mp2.x) * g0.y;
        float b0 = mp2.x - a0*g0.x;
        float a1 = (cip2.y - g1.x*mp2.y) * g1.y;
        float b1 = mp2.y - a1*g1.x;
        float2 oa; oa.x = a0; oa.y = a1;
        float2 ob2; ob2.x = b0; ob2.y = b1;
        stp(hF, y, sp, oa);
        stp(hP, y, sp, ob2);
    }
    __syncthreads();

    // ---- Phase C: vertical 11-sums of a,b; column-pair threads; row-slot in place ----
    // 37 pairs x 2 row-segs(32) x 2 arrays = 148 threads.
    // seg0: reads rows 0..41, writes 0..31. seg1: reads 32..73, writes 42..73.
    if (t < 148) {
        int arr = t & 1;
        int j2  = t >> 1;                    // 0..73
        int seg = (j2 >= 37) ? 1 : 0;
        int c2  = j2 - seg*37;
        int sp = c2 + ((c2 >= 19) ? 5 : 0);
        int y0 = seg*32;
        float* A = (arr ? hP : hF);
        float2 ring[11];
        float sx = 0.f, sy = 0.f;
        #pragma unroll
        for (int j = 0; j < 10; ++j) {
            float2 v = ldp(A, y0 + j, sp);
            ring[j] = v; sx += v.x; sy += v.y;
        }
        #pragma unroll
        for (int k = 0; k < 32; ++k) {
            int y = y0 + k;
            float2 v = ldp(A, y + 10, sp);
            sx += v.x; sy += v.y;
            int wrow = y + 10*seg;
            float2 o; o.x = sx; o.y = sy;
            stp(A, wrow, sp, o);
            sx -= ring[k%11].x; sy -= ring[k%11].y;
            ring[(k+10)%11] = v;
        }
    }
    __syncthreads();

    // ---- Phase D: horizontal 11-sums of summed a,b; pair trick; in place ----
    // 64 rows x 2 col-segs x 2 arrays = 256 threads; waves single-array (arr = t>=128).
    // seg0: reads slot-pairs {5..18,24,25}, writes pairs 0..15.
    // seg1: reads {16..18,24..41}, writes 26..41. Same-row; logical disjoint.
    if (t < 256) {
        int arr = (t >= 128) ? 1 : 0;
        int r2  = t - arr*128;               // 0..127
        int seg = r2 >> 6, row = r2 & 63;
        int prow = row + ((row >= 32) ? 10 : 0);
        float* A = (arr ? hP : hF);
        int xbp = seg*16;                    // base pair
        float2 ring[5];
        float T = 0.f;
        #pragma unroll
        for (int j = 0; j < 5; ++j) {
            int ip = xbp + j;
            int sp = ip + ((ip >= 19) ? 5 : 0);
            float2 v = ldp(A, prow, sp);
            ring[j] = v; T += v.x + v.y;
        }
        #pragma unroll
        for (int k2 = 0; k2 < 16; ++k2) {
            int ip = xbp + k2 + 5;
            int sp = ip + ((ip >= 19) ? 5 : 0);
            float2 p = ldp(A, prow, sp);
            float2 q = ring[k2 % 5];
            float O0 = T + p.x;
            float O1 = O0 + p.y - q.x;
            T = O1 - q.y;
            ring[k2 % 5] = p;
            float2 o; o.x = O0; o.y = O1;
            stp(A, prow, xbp + k2 + 10*seg, o);
        }
    }
    __syncthreads();

    // ---- Phase D2: combine + coalesced float2 store ----
    float* ob = out + (size_t)bd*HW;
    for (int i = t; i < TH*32; i += 512) {
        int y = i >> 5, c2 = i & 31;
        int prow = y + ((y >= 32) ? 10 : 0);
        int wp = c2 + ((c2 >= 16) ? 10 : 0);
        float2 ma2 = ldp(hF, prow, wp);
        float2 mb2 = ldp(hP, prow, wp);
        int gy = ty0 + y;
        int x0 = 2*c2;
        float2 im2 = *(const float2*)(ib + gy*WW + tx0 + x0);
        float2 o;
        o.x = (ma2.x*im2.x + mb2.x)*inv121;
        o.y = (ma2.y*im2.y + mb2.y)*inv121;
        *(float2*)(ob + gy*WW + tx0 + x0) = o;
    }
}

extern "C" void kernel_launch(void* const* d_in, const int* in_sizes, int n_in,
                              void* d_out, int out_size, void* d_ws, size_t ws_size,
                              hipStream_t stream) {
    const float* feat = (const float*)d_in[0];
    const float* img  = (const float*)d_in[1];
    float* out  = (float*)d_out;
    float2* miv = (float2*)d_ws;             // NB*HW float2 = 16 MiB

    img_stats<<<NB*128, 256, 0, stream>>>(img, miv);
    guided_main<<<NB*ND*64, 512, 0, stream>>>(feat, img, miv, out);
}

// Round 14
// 149.269 us; speedup vs baseline: 1.0759x; 1.0759x over previous
//
#include <hip/hip_runtime.h>

#define HH 512
#define WW 512
#define HW (512*512)
#define NB 8
#define ND 16
#define TW 64            // tile width (output)
#define TH 64            // tile height (output)
#define VR 74            // v-sum rows = TH+10
#define PT 86            // LDS pitch (pair-stride 43 == 11 mod 16, odd -> row-bijective)
#define GAP 20           // pad words between hF and hP: (VR*PT+GAP) % 32 == 16
                         // -> inter-array pair-bank shift = 8 -> interleaved waves disjoint

__device__ __forceinline__ int reflect(int v) {
    if (v < 0) v = -v;
    if (v >= HH) v = 2*HH - 2 - v;
    return v;
}

// ---------------- Prepass: {mean_I, 1/(var_I+eps)} interleaved float2 ----------------
// (R11 structure; same GAP trick for its two arrays)
__global__ __launch_bounds__(256) void img_stats(const float* __restrict__ img,
                                                 float2* __restrict__ miv) {
    const int VRs = 42, PTs = 86, THs = 32, TWs = 64;
    __shared__ __align__(16) float hBuf[2*VRs*PTs + 20];
    float* hF = hBuf;
    float* hP = hBuf + VRs*PTs + 20;         // gap 3612+20=3632 % 32 == 16

    int blk  = blockIdx.x;
    int tile = blk & 127;
    int b    = blk >> 7;
    int ty0  = (tile >> 3) * THs;
    int tx0  = (tile & 7)  * TWs;

    const float inv121 = 1.0f/121.0f;
    const float* ib = img + (size_t)b*HW;
    const int t = threadIdx.x;

    if (t < 252) {
        int seg = t / 84, col = t - seg*84;
        int gx = reflect(tx0 - 10 + col);
        const float* icol = ib + gx;
        int vr0 = seg*14;
        float rv[11], rq[11];
        float sv = 0.f, sq = 0.f;
        #pragma unroll
        for (int j = 0; j < 10; ++j) {
            int gy = reflect(ty0 - 10 + vr0 + j);
            float v = icol[gy*WW], q = v*v;
            rv[j] = v; rq[j] = q; sv += v; sq += q;
        }
        #pragma unroll
        for (int k = 0; k < 14; ++k) {
            int vr = vr0 + k;
            int gy = reflect(ty0 + vr);
            float v = icol[gy*WW], q = v*v;
            sv += v; sq += q;
            hF[vr*PTs + col] = sv;
            hP[vr*PTs + col] = sq;
            sv -= rv[k%11]; sq -= rq[k%11];
            rv[(k+10)%11] = v; rq[(k+10)%11] = q;
        }
    }
    __syncthreads();

    if (t < 168) {
        int arr = t & 1;
        int j2  = t >> 1;
        int seg = (j2 >= 42) ? 1 : 0;
        int vr  = j2 - seg*42;
        int xb = seg ? 38 : 0;
        int nout = seg ? 18 : 19;
        float* rA = (arr ? hP : hF) + vr*PTs;
        float2 ring[5];
        float T = 0.f;
        #pragma unroll
        for (int j = 0; j < 5; ++j) {
            float2 v = *(float2*)(rA + xb + 2*j);
            ring[j] = v; T += v.x + v.y;
        }
        #pragma unroll
        for (int k2 = 0; k2 < 19; ++k2) {
            if (k2 < nout) {
                int hc = xb + 2*k2;
                float2 p = *(float2*)(rA + hc + 10);
                float2 q = ring[k2 % 5];
                float O0 = T + p.x;
                float O1 = O0 + p.y - q.x;
                T = O1 - q.y;
                ring[k2 % 5] = p;
                float2 o; o.x = O0*inv121; o.y = O1*inv121;
                *(float2*)(rA + hc + 10*seg) = o;
            }
        }
    }
    __syncthreads();

    float2* mb = miv + (size_t)b*HW;
    for (int i = t; i < THs*TWs; i += 256) {
        int y = i >> 6, x = i & 63;
        int vr = y + 5, hc = x + 5;
        int slot = hc + ((hc >= 38) ? 10 : 0);
        float mI  = hF[vr*PTs + slot];
        float mII = hP[vr*PTs + slot];
        float var = mII - mI*mI;
        float2 o; o.x = mI; o.y = 1.0f / (var + 1e-8f);
        mb[(ty0 + y)*WW + tx0 + x] = o;
    }
}

// ---------------- Main fused kernel: one (b,d) channel, one 64x64 tile, 512 thr --------
// R12 structure byte-for-byte; only change: hF/hP share one buffer with a 20-word gap
// so the inter-array pair-bank shift is 8 (conflict-free quarter-waves everywhere).
// LDS: 2*74*86+20 words = 49.8 KB -> 3 blocks/CU x 8 waves = 24 waves/CU.
//   cols after B : slot(c) = c + 10*(c>=38)    (c in 0..73)
//   rows after C : prow(y) = y + 10*(y>=32)    (y in 0..63)
//   cols after D : wcol(x) = x + 20*(x>=32)    (x in 0..63)
__global__ __launch_bounds__(512) void guided_main(const float* __restrict__ feat,
                                                   const float* __restrict__ img,
                                                   const float2* __restrict__ miv,
                                                   float* __restrict__ out) {
    __shared__ __align__(16) float hBuf[2*VR*PT + GAP];
    float* hF = hBuf;
    float* hP = hBuf + VR*PT + GAP;          // gap 6364+20=6384 % 32 == 16

    int blk  = blockIdx.x;
    int tile = blk & 63;         // 8 col-tiles x 8 row-tiles
    int bd   = blk >> 6;
    int b    = bd >> 4;
    int ty0  = (tile >> 3) * TH;
    int tx0  = (tile & 7)  * TW;

    const float inv121 = 1.0f/121.0f;
    const float* fb   = feat + (size_t)bd*HW;
    const float* ib   = img  + (size_t)b*HW;
    const float2* mivb = miv + (size_t)b*HW;
    const int t = threadIdx.x;

    // ---- Phase A: vertical raw 11-sums of feat & img*feat (scalar, coalesced) ----
    // 84 cols x 6 row-segs (13 outputs each, guard vr<74) = 504 threads.
    if (t < 504) {
        int seg = t / 84, col = t - seg*84;
        int gx = reflect(tx0 - 10 + col);
        const float* fcol = fb + gx;
        const float* icol = ib + gx;
        int vr0 = seg*13;
        float rf[11], rp[11];
        float sf = 0.f, sp = 0.f;
        #pragma unroll
        for (int j = 0; j < 10; ++j) {
            int gy = reflect(ty0 - 10 + vr0 + j);
            float f = fcol[gy*WW], im = icol[gy*WW];
            float p = f*im;
            rf[j] = f; rp[j] = p; sf += f; sp += p;
        }
        #pragma unroll
        for (int k = 0; k < 13; ++k) {
            int vr = vr0 + k;
            if (vr < VR) {
                int gy = reflect(ty0 + vr);     // = ty0-10 + (vr+10)
                float f = fcol[gy*WW], im = icol[gy*WW];
                float p = f*im;
                sf += f; sp += p;
                hF[vr*PT + col] = sf;
                hP[vr*PT + col] = sp;
                sf -= rf[k%11]; sp -= rp[k%11];
                rf[(k+10)%11] = f; rp[(k+10)%11] = p;
            }
        }
    }
    __syncthreads();

    // ---- Phase B: horizontal 11-sums -> mp/cip (x inv121) in place at col-slots ----
    // 74 rows x 2 segs x 2 arrays = 296 threads; pair outputs via 10-sum trick.
    // seg0: reads raw 0..47, writes 0..37. seg1: reads raw 38..83, writes 48..83.
    if (t < 296) {
        int arr = t & 1;
        int j2  = t >> 1;                    // 0..147
        int seg = (j2 >= 74) ? 1 : 0;
        int vr  = j2 - seg*74;
        int xb = seg ? 38 : 0;
        int nout = seg ? 18 : 19;            // pairs
        float* rA = (arr ? hP : hF) + vr*PT;
        float2 ring[5];
        float T = 0.f;
        #pragma unroll
        for (int j = 0; j < 5; ++j) {
            float2 v = *(float2*)(rA + xb + 2*j);
            ring[j] = v; T += v.x + v.y;
        }
        #pragma unroll
        for (int k2 = 0; k2 < 19; ++k2) {
            if (k2 < nout) {
                int hc = xb + 2*k2;
                float2 p = *(float2*)(rA + hc + 10);
                float2 q = ring[k2 % 5];
                float O0 = T + p.x;
                float O1 = O0 + p.y - q.x;
                T = O1 - q.y;
                ring[k2 % 5] = p;
                float2 o; o.x = O0*inv121; o.y = O1*inv121;
                *(float2*)(rA + hc + 10*seg) = o;
            }
        }
    }
    __syncthreads();

    // ---- Phase B2: a,b elementwise on pairs; float2 miv loads; in place ----
    for (int i = t; i < VR*37; i += 512) {
        int y = i / 37, c2 = i - y*37;
        int x0 = 2*c2;
        int slot = x0 + ((x0 >= 38) ? 10 : 0);
        float* pF = &hF[y*PT + slot];
        float* pP = &hP[y*PT + slot];
        float2 mp2  = *(float2*)pF;
        float2 cip2 = *(float2*)pP;
        int gy = reflect(ty0 - 5 + y);
        const float2* mrow = mivb + gy*WW;
        int gx0 = tx0 - 5 + x0;
        float2 g0 = mrow[reflect(gx0)];
        float2 g1 = mrow[reflect(gx0+1)];
        float a0 = (cip2.x - g0.x*mp2.x) * g0.y;
        float b0 = mp2.x - a0*g0.x;
        float a1 = (cip2.y - g1.x*mp2.y) * g1.y;
        float b1 = mp2.y - a1*g1.x;
        float2 oa; oa.x = a0; oa.y = a1;
        float2 ob2; ob2.x = b0; ob2.y = b1;
        *(float2*)pF = oa;
        *(float2*)pP = ob2;
    }
    __syncthreads();

    // ---- Phase C: vertical 11-sums of a,b; column-pair threads; row-slot in place ----
    // 37 pairs x 2 row-segs(32) x 2 arrays = 148 threads.
    // seg0: reads rows 0..41, writes 0..31. seg1: reads 32..73, writes 42..73.
    if (t < 148) {
        int arr = t & 1;
        int j2  = t >> 1;                    // 0..73
        int seg = (j2 >= 37) ? 1 : 0;
        int c2  = j2 - seg*37;
        int x0 = 2*c2;
        int slotc = x0 + ((x0 >= 38) ? 10 : 0);
        int y0 = seg*32;
        float* A = (arr ? hP : hF);
        float2 ring[11];
        float sx = 0.f, sy = 0.f;
        #pragma unroll
        for (int j = 0; j < 10; ++j) {
            float2 v = *(float2*)(A + (y0+j)*PT + slotc);
            ring[j] = v; sx += v.x; sy += v.y;
        }
        #pragma unroll
        for (int k = 0; k < 32; ++k) {
            int y = y0 + k;
            float2 v = *(float2*)(A + (y+10)*PT + slotc);
            sx += v.x; sy += v.y;
            int wrow = y + 10*seg;
            float2 o; o.x = sx; o.y = sy;
            *(float2*)(A + wrow*PT + slotc) = o;
            sx -= ring[k%11].x; sy -= ring[k%11].y;
            ring[(k+10)%11] = v;
        }
    }
    __syncthreads();

    // ---- Phase D: horizontal 11-sums of summed a,b; pair trick; in place ----
    // 64 rows x 2 arrays x 2 col-segs = 256 threads.
    // seg0: reads slots{0..37,48..51}, writes cols 0..31. seg1: reads {32..37,48..83},
    // writes 52..83.
    if (t < 256) {
        int arr = t & 1;
        int r2  = t >> 1;                    // 0..127
        int seg = r2 >> 6, row = r2 & 63;
        int prow = row + ((row >= 32) ? 10 : 0);
        float* rA = (arr ? hP : hF) + prow*PT;
        int xb = seg*32;
        float2 ring[5];
        float T = 0.f;
        #pragma unroll
        for (int j = 0; j < 5; ++j) {
            int idx = xb + 2*j;
            int sl = idx + ((idx >= 38) ? 10 : 0);
            float2 v = *(float2*)(rA + sl);
            ring[j] = v; T += v.x + v.y;
        }
        #pragma unroll
        for (int k2 = 0; k2 < 16; ++k2) {
            int x = xb + 2*k2;
            int idx = x + 10;
            int sl = idx + ((idx >= 38) ? 10 : 0);
            float2 p = *(float2*)(rA + sl);
            float2 q = ring[k2 % 5];
            float O0 = T + p.x;
            float O1 = O0 + p.y - q.x;
            T = O1 - q.y;
            ring[k2 % 5] = p;
            int wcol = x + 20*seg;
            float2 o; o.x = O0; o.y = O1;
            *(float2*)(rA + wcol) = o;
        }
    }
    __syncthreads();

    // ---- Phase D2: combine + coalesced float2 store ----
    float* ob = out + (size_t)bd*HW;
    for (int i = t; i < TH*32; i += 512) {
        int y = i >> 5, c2 = i & 31;
        int x0 = 2*c2;
        int prow = y + ((y >= 32) ? 10 : 0);
        int wcol = (x0 < 32) ? x0 : x0 + 20;
        float2 ma2 = *(float2*)(&hF[prow*PT + wcol]);
        float2 mb2 = *(float2*)(&hP[prow*PT + wcol]);
        int gy = ty0 + y;
        float2 im2 = *(const float2*)(ib + gy*WW + tx0 + x0);
        float2 o;
        o.x = (ma2.x*im2.x + mb2.x)*inv121;
        o.y = (ma2.y*im2.y + mb2.y)*inv121;
        *(float2*)(ob + gy*WW + tx0 + x0) = o;
    }
}

extern "C" void kernel_launch(void* const* d_in, const int* in_sizes, int n_in,
                              void* d_out, int out_size, void* d_ws, size_t ws_size,
                              hipStream_t stream) {
    const float* feat = (const float*)d_in[0];
    const float* img  = (const float*)d_in[1];
    float* out  = (float*)d_out;
    float2* miv = (float2*)d_ws;             // NB*HW float2 = 16 MiB

    img_stats<<<NB*128, 256, 0, stream>>>(img, miv);
    guided_main<<<NB*ND*64, 512, 0, stream>>>(feat, img, miv, out);
}